// Round 1
// 129.659 us; speedup vs baseline: 1.0877x; 1.0877x over previous
//
#include <hip/hip_runtime.h>
#include <hip/hip_bf16.h>

#define N_NODES 50000
#define N_EDGES 600000
#define BN_EPS 1e-5f
#define ELL_MAX 64   // P(deg>=64) ~ 1e-30 for Binomial(600k, 1/50k)

typedef short bf16x8 __attribute__((ext_vector_type(8)));
typedef float f32x4 __attribute__((ext_vector_type(4)));

__device__ __forceinline__ ushort f2bf(float f) {
    unsigned u = __float_as_uint(f);
    u += 0x7fffu + ((u >> 16) & 1u);
    return (ushort)(u >> 16);
}
__device__ __forceinline__ float bf_lo(unsigned u) { return __uint_as_float(u << 16); }
__device__ __forceinline__ float bf_hi(unsigned u) { return __uint_as_float(u & 0xffff0000u); }

// ===========================================================================
// prep_fill: [conv x->bf16 | weight transpose | bn fold | ELL fill] in one
// launch. cnt zeroed beforehand by hipMemsetAsync.
// W1T: [128 out][256 K]  (K 0..127 = W1l for AGG, 128..255 = W1r for SELF)
// W2T2:[128 out][128 K]  (out 0..63 = W2l -> Q, 64..127 = W2r -> R)
// ===========================================================================
#define T_CONV  (N_NODES * 32)                 // 1,600,000
#define T_W     (128 * 256 + 128 * 128)        // 49,152
#define T_BN    128
#define T_TOTAL (T_CONV + T_W + T_BN + N_EDGES)

__global__ __launch_bounds__(256) void prep_fill_kernel(
    const float* __restrict__ x,
    const float* __restrict__ W1l, const float* __restrict__ W1r,
    const float* __restrict__ W2l, const float* __restrict__ W2r,
    const float* __restrict__ gamma, const float* __restrict__ beta,
    const float* __restrict__ mean, const float* __restrict__ var,
    const float* __restrict__ b1, const int* __restrict__ eidx,
    ushort* __restrict__ Xb, ushort* __restrict__ W1T, ushort* __restrict__ W2T2,
    float* __restrict__ scale_, float* __restrict__ shift_,
    int* __restrict__ cnt, ushort* __restrict__ ell) {
    int t = blockIdx.x * 256 + threadIdx.x;
    if (t < T_CONV) {
        int row = t >> 5, c4 = t & 31;
        float4 v = *(const float4*)(x + (size_t)row * 128 + c4 * 4);
        ushort4 o;
        o.x = f2bf(v.x); o.y = f2bf(v.y); o.z = f2bf(v.z); o.w = f2bf(v.w);
        *(ushort4*)(Xb + (size_t)row * 128 + c4 * 4) = o;
    } else if (t < T_CONV + T_W) {
        int t2 = t - T_CONV;
        if (t2 < 128 * 256) {
            int c = t2 >> 8, k = t2 & 255;
            float v = (k < 128) ? W1l[k * 128 + c] : W1r[(k - 128) * 128 + c];
            W1T[c * 256 + k] = f2bf(v);
        } else {
            int t3 = t2 - 128 * 256;            // 0..16383
            int c = t3 >> 7, k = t3 & 127;
            float v = (c < 64) ? W2l[k * 64 + c] : W2r[k * 64 + (c - 64)];
            W2T2[c * 128 + k] = f2bf(v);
        }
    } else if (t < T_CONV + T_W + T_BN) {
        int c = t - (T_CONV + T_W);
        float sc = gamma[c] * rsqrtf(var[c] + BN_EPS);
        scale_[c] = sc;
        shift_[c] = sc * (b1[c] - mean[c]) + beta[c];
    } else if (t < T_TOTAL) {
        int e = t - (T_CONV + T_W + T_BN);
        int d = eidx[N_EDGES + e];
        int p = atomicAdd(&cnt[d], 1);
        if (p < ELL_MAX) ell[(size_t)d * ELL_MAX + p] = (ushort)eidx[e];
    }
}

// ===========================================================================
// fused1: per 64-row block:
//   phase A: self-stage Xb -> sA granules 16..31 ; gather-mean(Xb) -> 0..15
//   phase B: MFMA1  H = relu(bn([agg|self] @ W1T^T))  (64x128, regs)
//   phase C: H -> sH (reuse of sA, 16KB, swizzled)
//   phase D: MFMA2  [Q|R] = H @ W2T2^T ; Q bf16 out, R = .. + b2 fp32 out
// H never touches HBM; layer-2 gather operand shrinks to 64ch.
// ===========================================================================
__global__ __launch_bounds__(256) void fused1_kernel(
    const ushort* __restrict__ Xb, const ushort* __restrict__ ell,
    const int* __restrict__ cnt,
    const ushort* __restrict__ W1T, const ushort* __restrict__ W2T2,
    const float* __restrict__ scale_, const float* __restrict__ shift_,
    const float* __restrict__ b2,
    ushort* __restrict__ Q, float* __restrict__ R) {
    __shared__ unsigned sAd[64 * 32 * 4];   // 32 KB
    const int tid = threadIdx.x;
    const int row0 = blockIdx.x * 64;

    // ---- phase A1: self rows -> granules 16..31 (coalesced) ----
    #pragma unroll
    for (int i = 0; i < 4; ++i) {
        int g = i * 256 + tid;                // 0..1023
        int r = g >> 4, gs = g & 15;
        int row = row0 + r;
        uint4 v = make_uint4(0, 0, 0, 0);
        if (row < N_NODES) v = *(const uint4*)(Xb + ((size_t)row << 7) + gs * 8);
        *(uint4*)&sAd[((r << 5) + ((16 + gs) ^ (r & 7))) << 2] = v;
    }

    // ---- phase A2: gather-mean -> granules 0..15 ----
    // 16 lanes per node (lane = 8 ch = one granule), 4 concurrent nodes/wave.
    const int w = tid >> 6, l = tid & 63;
    const int grp = l >> 4, lane16 = l & 15;
    for (int kq = 0; kq < 4; ++kq) {
        const int r = w * 16 + kq * 4 + grp;
        const int node = row0 + r;
        float a0 = 0.f, a1 = 0.f, a2 = 0.f, a3 = 0.f;
        float a4 = 0.f, a5 = 0.f, a6 = 0.f, a7 = 0.f;
        float ic = 0.f;
        if (node < N_NODES) {
            const int deg = cnt[node];
            const int end = deg < ELL_MAX ? deg : ELL_MAX;
            const ushort* rowp = ell + (size_t)node * ELL_MAX;
            int j = 0;
            for (; j + 4 <= end; j += 4) {
                ushort4 ss = *(const ushort4*)(rowp + j);
                uint4 u0 = *(const uint4*)(Xb + ((size_t)ss.x << 7) + lane16 * 8);
                uint4 u1 = *(const uint4*)(Xb + ((size_t)ss.y << 7) + lane16 * 8);
                uint4 u2 = *(const uint4*)(Xb + ((size_t)ss.z << 7) + lane16 * 8);
                uint4 u3 = *(const uint4*)(Xb + ((size_t)ss.w << 7) + lane16 * 8);
                a0 += bf_lo(u0.x) + bf_lo(u1.x) + bf_lo(u2.x) + bf_lo(u3.x);
                a1 += bf_hi(u0.x) + bf_hi(u1.x) + bf_hi(u2.x) + bf_hi(u3.x);
                a2 += bf_lo(u0.y) + bf_lo(u1.y) + bf_lo(u2.y) + bf_lo(u3.y);
                a3 += bf_hi(u0.y) + bf_hi(u1.y) + bf_hi(u2.y) + bf_hi(u3.y);
                a4 += bf_lo(u0.z) + bf_lo(u1.z) + bf_lo(u2.z) + bf_lo(u3.z);
                a5 += bf_hi(u0.z) + bf_hi(u1.z) + bf_hi(u2.z) + bf_hi(u3.z);
                a6 += bf_lo(u0.w) + bf_lo(u1.w) + bf_lo(u2.w) + bf_lo(u3.w);
                a7 += bf_hi(u0.w) + bf_hi(u1.w) + bf_hi(u2.w) + bf_hi(u3.w);
            }
            for (; j < end; ++j) {
                int s = rowp[j];
                uint4 u = *(const uint4*)(Xb + ((size_t)s << 7) + lane16 * 8);
                a0 += bf_lo(u.x); a1 += bf_hi(u.x);
                a2 += bf_lo(u.y); a3 += bf_hi(u.y);
                a4 += bf_lo(u.z); a5 += bf_hi(u.z);
                a6 += bf_lo(u.w); a7 += bf_hi(u.w);
            }
            ic = 1.0f / fmaxf((float)deg, 1.0f);
        }
        uint4 o;
        o.x = (unsigned)f2bf(a0 * ic) | ((unsigned)f2bf(a1 * ic) << 16);
        o.y = (unsigned)f2bf(a2 * ic) | ((unsigned)f2bf(a3 * ic) << 16);
        o.z = (unsigned)f2bf(a4 * ic) | ((unsigned)f2bf(a5 * ic) << 16);
        o.w = (unsigned)f2bf(a6 * ic) | ((unsigned)f2bf(a7 * ic) << 16);
        *(uint4*)&sAd[((r << 5) + (lane16 ^ (r & 7))) << 2] = o;
    }
    __syncthreads();

    // ---- phase B: MFMA1 ----
    const bf16x8* sA8 = (const bf16x8*)sAd;
    const int wr = (w >> 1) * 32;
    const int wc = (w & 1) * 64;
    const int lr = l & 15, lk = l >> 4;

    f32x4 acc[2][4];
    #pragma unroll
    for (int mi = 0; mi < 2; ++mi)
        #pragma unroll
        for (int ni = 0; ni < 4; ++ni) acc[mi][ni] = (f32x4){0.f, 0.f, 0.f, 0.f};

    #pragma unroll
    for (int kk = 0; kk < 8; ++kk) {
        bf16x8 a[2], b[4];
        #pragma unroll
        for (int mi = 0; mi < 2; ++mi) {
            int r = wr + mi * 16 + lr;
            a[mi] = sA8[(r << 5) + ((kk * 4 + lk) ^ (r & 7))];
        }
        #pragma unroll
        for (int ni = 0; ni < 4; ++ni) {
            int c = wc + ni * 16 + lr;
            b[ni] = *(const bf16x8*)(W1T + (size_t)c * 256 + kk * 32 + lk * 8);
        }
        #pragma unroll
        for (int mi = 0; mi < 2; ++mi)
            #pragma unroll
            for (int ni = 0; ni < 4; ++ni)
                acc[mi][ni] = __builtin_amdgcn_mfma_f32_16x16x32_bf16(
                    b[ni], a[mi], acc[mi][ni], 0, 0, 0);
    }
    __syncthreads();   // all waves done reading sA before H overwrites it

    // ---- phase C: bn+relu, H (bf16) -> sH = sAd[0..16KB), [64 r][16 g] swz ----
    #pragma unroll
    for (int ni = 0; ni < 4; ++ni) {
        int c0 = wc + ni * 16 + lk * 4;
        float4 sc = *(const float4*)(scale_ + c0);
        float4 sh = *(const float4*)(shift_ + c0);
        int g = c0 >> 3;
        int sub = (c0 & 4) ? 8 : 0;
        #pragma unroll
        for (int mi = 0; mi < 2; ++mi) {
            int r = wr + mi * 16 + lr;
            float h0 = fmaxf(acc[mi][ni][0] * sc.x + sh.x, 0.f);
            float h1 = fmaxf(acc[mi][ni][1] * sc.y + sh.y, 0.f);
            float h2 = fmaxf(acc[mi][ni][2] * sc.z + sh.z, 0.f);
            float h3 = fmaxf(acc[mi][ni][3] * sc.w + sh.w, 0.f);
            uint2 o;
            o.x = (unsigned)f2bf(h0) | ((unsigned)f2bf(h1) << 16);
            o.y = (unsigned)f2bf(h2) | ((unsigned)f2bf(h3) << 16);
            *(uint2*)((char*)sAd + (((r << 4) + (g ^ (r & 7))) << 4) + sub) = o;
        }
    }
    __syncthreads();

    // ---- phase D: MFMA2  [Q|R] = H @ W2T2^T  (wave w owns rows w*16..+15) ----
    f32x4 acc2[8];
    #pragma unroll
    for (int ni = 0; ni < 8; ++ni) acc2[ni] = (f32x4){0.f, 0.f, 0.f, 0.f};

    const int r2 = w * 16 + lr;
    #pragma unroll
    for (int kk = 0; kk < 4; ++kk) {
        bf16x8 a = *(const bf16x8*)((const char*)sAd +
                                    (((r2 << 4) + ((kk * 4 + lk) ^ (r2 & 7))) << 4));
        #pragma unroll
        for (int ni = 0; ni < 8; ++ni) {
            const bf16x8 b = *(const bf16x8*)(W2T2 + (size_t)(ni * 16 + lr) * 128 +
                                              kk * 32 + lk * 8);
            acc2[ni] = __builtin_amdgcn_mfma_f32_16x16x32_bf16(b, a, acc2[ni], 0, 0, 0);
        }
    }

    const int rowo = row0 + r2;
    if (rowo < N_NODES) {
        #pragma unroll
        for (int ni = 0; ni < 4; ++ni) {
            int c0 = ni * 16 + lk * 4;
            ushort4 o;
            o.x = f2bf(acc2[ni][0]); o.y = f2bf(acc2[ni][1]);
            o.z = f2bf(acc2[ni][2]); o.w = f2bf(acc2[ni][3]);
            *(ushort4*)(Q + ((size_t)rowo << 6) + c0) = o;
        }
        #pragma unroll
        for (int ni = 4; ni < 8; ++ni) {
            int c0 = (ni - 4) * 16 + lk * 4;
            float4 bias = *(const float4*)(b2 + c0);
            float4 o;
            o.x = acc2[ni][0] + bias.x; o.y = acc2[ni][1] + bias.y;
            o.z = acc2[ni][2] + bias.z; o.w = acc2[ni][3] + bias.w;
            *(float4*)(R + ((size_t)rowo << 6) + c0) = o;
        }
    }
}

// ===========================================================================
// finish: out[n] = mean_j Q[j] + R[n]    (R already includes b2)
// 16 lanes per node (lane = 4 ch), 16 nodes per block.
// ===========================================================================
__global__ __launch_bounds__(256) void finish_kernel(
    const ushort* __restrict__ Q, const float* __restrict__ R,
    const ushort* __restrict__ ell, const int* __restrict__ cnt,
    float* __restrict__ out) {
    const int tid = threadIdx.x;
    const int grp = tid >> 4, lane16 = tid & 15;
    const int node = blockIdx.x * 16 + grp;
    if (node >= N_NODES) return;
    const int deg = cnt[node];
    const int end = deg < ELL_MAX ? deg : ELL_MAX;
    const ushort* rowp = ell + (size_t)node * ELL_MAX;
    float a0 = 0.f, a1 = 0.f, a2 = 0.f, a3 = 0.f;
    int j = 0;
    for (; j + 4 <= end; j += 4) {
        ushort4 ss = *(const ushort4*)(rowp + j);
        uint2 u0 = *(const uint2*)(Q + ((size_t)ss.x << 6) + lane16 * 4);
        uint2 u1 = *(const uint2*)(Q + ((size_t)ss.y << 6) + lane16 * 4);
        uint2 u2 = *(const uint2*)(Q + ((size_t)ss.z << 6) + lane16 * 4);
        uint2 u3 = *(const uint2*)(Q + ((size_t)ss.w << 6) + lane16 * 4);
        a0 += bf_lo(u0.x) + bf_lo(u1.x) + bf_lo(u2.x) + bf_lo(u3.x);
        a1 += bf_hi(u0.x) + bf_hi(u1.x) + bf_hi(u2.x) + bf_hi(u3.x);
        a2 += bf_lo(u0.y) + bf_lo(u1.y) + bf_lo(u2.y) + bf_lo(u3.y);
        a3 += bf_hi(u0.y) + bf_hi(u1.y) + bf_hi(u2.y) + bf_hi(u3.y);
    }
    for (; j < end; ++j) {
        int s = rowp[j];
        uint2 u = *(const uint2*)(Q + ((size_t)s << 6) + lane16 * 4);
        a0 += bf_lo(u.x); a1 += bf_hi(u.x);
        a2 += bf_lo(u.y); a3 += bf_hi(u.y);
    }
    float ic = 1.0f / fmaxf((float)deg, 1.0f);
    float4 r4 = *(const float4*)(R + ((size_t)node << 6) + lane16 * 4);
    float4 o;
    o.x = a0 * ic + r4.x;
    o.y = a1 * ic + r4.y;
    o.z = a2 * ic + r4.z;
    o.w = a3 * ic + r4.w;
    *(float4*)(out + ((size_t)node << 6) + lane16 * 4) = o;
}

// ---------------------------------------------------------------------------
extern "C" void kernel_launch(void* const* d_in, const int* in_sizes, int n_in,
                              void* d_out, int out_size, void* d_ws, size_t ws_size,
                              hipStream_t stream) {
    const float* x     = (const float*)d_in[0];
    const int*   eidx  = (const int*)d_in[1];
    const float* W1_l  = (const float*)d_in[2];
    const float* W1_r  = (const float*)d_in[3];
    const float* b1    = (const float*)d_in[4];
    const float* gamma = (const float*)d_in[5];
    const float* beta  = (const float*)d_in[6];
    const float* mean  = (const float*)d_in[7];
    const float* var   = (const float*)d_in[8];
    const float* W2_l  = (const float*)d_in[9];
    const float* W2_r  = (const float*)d_in[10];
    const float* b2    = (const float*)d_in[11];
    float* out = (float*)d_out;

    char* p = (char*)d_ws;
    ushort* Xb   = (ushort*)p; p += (size_t)N_NODES * 128 * 2;       // 12.8 MB
    ushort* Q    = (ushort*)p; p += (size_t)N_NODES * 64 * 2;        //  6.4 MB
    float*  R    = (float*)p;  p += (size_t)N_NODES * 64 * 4;        // 12.8 MB
    ushort* W1T  = (ushort*)p; p += 128 * 256 * 2;
    ushort* W2T2 = (ushort*)p; p += 128 * 128 * 2;
    float* scale_ = (float*)p; p += 128 * 4;
    float* shift_ = (float*)p; p += 128 * 4;
    ushort* ell  = (ushort*)p; p += (size_t)N_NODES * ELL_MAX * 2;   //  6.4 MB
    int* cnt     = (int*)p;    p += (size_t)N_NODES * 4;

    hipMemsetAsync(cnt, 0, (size_t)N_NODES * sizeof(int), stream);

    prep_fill_kernel<<<(T_TOTAL + 255) / 256, 256, 0, stream>>>(
        x, W1_l, W1_r, W2_l, W2_r, gamma, beta, mean, var, b1, eidx,
        Xb, W1T, W2T2, scale_, shift_, cnt, ell);

    fused1_kernel<<<(N_NODES + 63) / 64, 256, 0, stream>>>(
        Xb, ell, cnt, W1T, W2T2, scale_, shift_, b2, Q, R);

    finish_kernel<<<(N_NODES + 15) / 16, 256, 0, stream>>>(Q, R, ell, cnt, out);
}